// Round 7
// baseline (1587.687 us; speedup 1.0000x reference)
//
#include <hip/hip_runtime.h>
#include <hip/hip_bf16.h>
#include <math.h>

#define N_NODES 100000
#define N_EDGES 1600000
#define DIN 256
#define KTOT 512
#define SLOTS 64   // bucket capacity; deg ~ Poisson(16), P(>=64) ~ 1e-19

typedef __attribute__((ext_vector_type(8))) short frag_ab;   // 8 bf16
typedef __attribute__((ext_vector_type(4))) float frag_cd;   // 4 fp32

__device__ inline unsigned short f2bf(float f) {
    union { float f; unsigned u; } v; v.f = f;
    unsigned r = v.u + 0x7FFF + ((v.u >> 16) & 1);
    return (unsigned short)(r >> 16);
}
__device__ inline float bf2f(unsigned u16) {
    union { unsigned u; float f; } v; v.u = u16 << 16;
    return v.f;
}
__device__ inline float bf_lo(unsigned u) {
    union { unsigned u; float f; } v; v.u = u << 16; return v.f;
}
__device__ inline float bf_hi(unsigned u) {
    union { unsigned u; float f; } v; v.u = u & 0xffff0000u; return v.f;
}

// ======== prep mega-kernel: bucket-CSR + x->bf16 + weight transposes, one launch ========
// blocks [0,6250): bucket build; [6250,7402): weights; [7402,32402): conv x
__global__ __launch_bounds__(256) void prep(
    const int* __restrict__ src, const int* __restrict__ dst,
    int* __restrict__ cnt, int* __restrict__ col,
    const float* __restrict__ x, unsigned short* __restrict__ xbf,
    const float* __restrict__ Wl0, const float* __restrict__ Wr0,
    const float* __restrict__ Wl1, const float* __restrict__ Wr1,
    const float* __restrict__ Wl2, const float* __restrict__ Wr2,
    unsigned short* __restrict__ Wt0, unsigned short* __restrict__ Wt1,
    unsigned short* __restrict__ Wl2t, unsigned short* __restrict__ Wr2t) {
    int b = blockIdx.x;
    int tid = threadIdx.x;
    if (b < 6250) {
        int e = b * 256 + tid;   // < 1.6M exactly
        int d = dst[e];
        int pos = atomicAdd(&cnt[d], 1);
        if (pos < SLOTS) col[(size_t)d * SLOTS + pos] = src[e];
    } else if (b < 7402) {
        int idx = (b - 6250) * 256 + tid;
        if (idx < 262144) {
            const float* Wl = (idx < 131072) ? Wl0 : Wl1;
            const float* Wr = (idx < 131072) ? Wr0 : Wr1;
            unsigned short* Wt = (idx < 131072) ? Wt0 : Wt1;
            int i = idx & 131071;
            int n = i >> 9, k = i & 511;
            float v = (k < 256) ? Wl[k * 256 + n] : Wr[(k - 256) * 256 + n];
            Wt[i] = f2bf(v);
        } else if (idx < 294912) {
            const float* W = (idx < 278528) ? Wl2 : Wr2;
            unsigned short* Wt = (idx < 278528) ? Wl2t : Wr2t;
            int i = (idx - 262144) & 16383;
            int n = i >> 8, k = i & 255;
            Wt[i] = f2bf((n < 40) ? W[k * 40 + n] : 0.f);
        }
    } else {
        int i = (b - 7402) * 256 + tid;  // < 6.4M exactly
        float4 v = ((const float4*)x)[i];
        uint2 o;
        o.x = (unsigned)f2bf(v.x) | ((unsigned)f2bf(v.y) << 16);
        o.y = (unsigned)f2bf(v.z) | ((unsigned)f2bf(v.w) << 16);
        ((uint2*)xbf)[i] = o;
    }
}

// ======== channel-tiled gather-mean ========
// W = row width (bf16 elems). Grid: (nodes/4, W/16). Per tile the feature slice is
// 100K*16*2B = 3.2 MB -> fits per-XCD L2, so random row reads are L2 hits.
// Wave = 1 node; 8 edge-groups x 8 sublanes; sublane covers 2 channels (dword).
template <int W>
__global__ __launch_bounds__(256) void gather_tile(
    const int* __restrict__ cnt, const int* __restrict__ col,
    const unsigned short* __restrict__ h, unsigned short* __restrict__ mean, int nNodes) {
    int node = blockIdx.x * 4 + (threadIdx.x >> 6);
    int tile = blockIdx.y;
    int lane = threadIdx.x & 63;
    if (node >= nNodes) return;
    int deg = cnt[node];
    int nd = (deg < SLOTS) ? deg : SLOTS;
    const int* cp = col + (size_t)node * SLOTS;
    int g = lane >> 3;       // edge group 0..7
    int sl = lane & 7;       // channel pair 0..7
    const unsigned short* hb = h + tile * 16 + sl * 2;
    float a0 = 0.f, a1 = 0.f;
    int e = 0;
    for (; e + 16 <= nd; e += 16) {
        int s0 = cp[e + g];
        int s1 = cp[e + 8 + g];
        unsigned v0 = *(const unsigned*)(hb + (size_t)s0 * W);
        unsigned v1 = *(const unsigned*)(hb + (size_t)s1 * W);
        a0 += bf_lo(v0) + bf_lo(v1);
        a1 += bf_hi(v0) + bf_hi(v1);
    }
    if (e + 8 <= nd) {
        int s = cp[e + g];
        unsigned v = *(const unsigned*)(hb + (size_t)s * W);
        a0 += bf_lo(v); a1 += bf_hi(v);
        e += 8;
    }
    int rem = nd - e;
    if (g < rem) {
        int s = cp[e + g];
        unsigned v = *(const unsigned*)(hb + (size_t)s * W);
        a0 += bf_lo(v); a1 += bf_hi(v);
    }
    a0 += __shfl_xor(a0, 8);  a1 += __shfl_xor(a1, 8);
    a0 += __shfl_xor(a0, 16); a1 += __shfl_xor(a1, 16);
    a0 += __shfl_xor(a0, 32); a1 += __shfl_xor(a1, 32);
    if (g == 0) {
        float inv = 1.0f / fmaxf((float)deg, 1.0f);
        unsigned o = (unsigned)f2bf(a0 * inv) | ((unsigned)f2bf(a1 * inv) << 16);
        *(unsigned*)(mean + (size_t)node * W + tile * 16 + sl * 2) = o;
    }
}

// ---- MFMA dual-GEMM (layers 0/1): out = relu([mean;h] @ Wt^T + b), bf16 out ----
__global__ __launch_bounds__(256) void sage_mfma(
    const unsigned short* __restrict__ mean, const unsigned short* __restrict__ h,
    const unsigned short* __restrict__ Wt, const float* __restrict__ bias,
    unsigned short* __restrict__ out, int nNodes) {
    __shared__ unsigned short sA[64][32];
    __shared__ unsigned short sB[256][32];

    int tid = threadIdx.x;
    int wave = tid >> 6;
    int lane = tid & 63;
    int lrow = lane & 15;
    int quad = lane >> 4;
    int node0 = blockIdx.x * 64;

    frag_cd acc[4][4];
#pragma unroll
    for (int mi = 0; mi < 4; mi++)
#pragma unroll
        for (int ni = 0; ni < 4; ni++) acc[mi][ni] = (frag_cd){0.f, 0.f, 0.f, 0.f};

    int ar = tid >> 2;
    int ak = (tid & 3) * 8;
    int aNode = node0 + ar;

    for (int kb = 0; kb < KTOT; kb += 32) {
        {
            const unsigned short* srcp = (kb < 256)
                ? (mean + (size_t)aNode * DIN + kb + ak)
                : (h + (size_t)aNode * DIN + (kb - 256) + ak);
            uint4 av = {0u, 0u, 0u, 0u};
            if (aNode < nNodes) av = *(const uint4*)srcp;
            *(uint4*)(&sA[ar][ak]) = av;
        }
        {
            const unsigned short* wp = Wt + (size_t)tid * KTOT + kb;
#pragma unroll
            for (int j = 0; j < 4; j++)
                *(uint4*)(&sB[tid][j * 8]) = *(const uint4*)(wp + j * 8);
        }
        __syncthreads();

        frag_ab aF[4], bF[4];
#pragma unroll
        for (int mi = 0; mi < 4; mi++)
            aF[mi] = *(const frag_ab*)(&sA[mi * 16 + lrow][quad * 8]);
#pragma unroll
        for (int ni = 0; ni < 4; ni++)
            bF[ni] = *(const frag_ab*)(&sB[(wave * 4 + ni) * 16 + lrow][quad * 8]);

#pragma unroll
        for (int mi = 0; mi < 4; mi++)
#pragma unroll
            for (int ni = 0; ni < 4; ni++)
                acc[mi][ni] = __builtin_amdgcn_mfma_f32_16x16x32_bf16(
                    aF[mi], bF[ni], acc[mi][ni], 0, 0, 0);
        __syncthreads();
    }

#pragma unroll
    for (int ni = 0; ni < 4; ni++) {
        int colc = (wave * 4 + ni) * 16 + lrow;
        float bv = bias[colc];
#pragma unroll
        for (int mi = 0; mi < 4; mi++) {
#pragma unroll
            for (int r = 0; r < 4; r++) {
                int node = node0 + mi * 16 + quad * 4 + r;
                if (node < nNodes) {
                    float v = fmaxf(acc[mi][ni][r] + bv, 0.f);
                    out[(size_t)node * 256 + colc] = f2bf(v);
                }
            }
        }
    }
}

// ---------------- z = h @ Wt64^T (K=256, 64 cols, bf16 out, no bias) ----------------
__global__ __launch_bounds__(256) void mfma_lin64(
    const unsigned short* __restrict__ h, const unsigned short* __restrict__ Wt,
    unsigned short* __restrict__ z, int nNodes) {
    __shared__ unsigned short sA[64][32];
    __shared__ unsigned short sB[64][32];

    int tid = threadIdx.x;
    int wave = tid >> 6;
    int lane = tid & 63;
    int lrow = lane & 15;
    int quad = lane >> 4;
    int node0 = blockIdx.x * 64;

    frag_cd acc[4];
#pragma unroll
    for (int ni = 0; ni < 4; ni++) acc[ni] = (frag_cd){0.f, 0.f, 0.f, 0.f};

    int ar = tid >> 2;
    int ak = (tid & 3) * 8;
    int aNode = node0 + ar;

    for (int kb = 0; kb < 256; kb += 32) {
        uint4 av = {0u, 0u, 0u, 0u};
        if (aNode < nNodes) av = *(const uint4*)(h + (size_t)aNode * DIN + kb + ak);
        *(uint4*)(&sA[ar][ak]) = av;
        *(uint4*)(&sB[ar][ak]) = *(const uint4*)(Wt + (size_t)ar * 256 + kb + ak);
        __syncthreads();

        frag_ab aF = *(const frag_ab*)(&sA[wave * 16 + lrow][quad * 8]);
#pragma unroll
        for (int ni = 0; ni < 4; ni++) {
            frag_ab bF = *(const frag_ab*)(&sB[ni * 16 + lrow][quad * 8]);
            acc[ni] = __builtin_amdgcn_mfma_f32_16x16x32_bf16(aF, bF, acc[ni], 0, 0, 0);
        }
        __syncthreads();
    }

#pragma unroll
    for (int ni = 0; ni < 4; ni++) {
        int colc = ni * 16 + lrow;
#pragma unroll
        for (int r = 0; r < 4; r++) {
            int node = node0 + wave * 16 + quad * 4 + r;
            if (node < nNodes)
                z[(size_t)node * 64 + colc] = f2bf(acc[ni][r]);
        }
    }
}

// ------- final: out = log_softmax(h2 @ Wr2t^T + mean_z + b2), fp32 out (40 cols) -------
__global__ __launch_bounds__(256) void sage_out(
    const unsigned short* __restrict__ h, const unsigned short* __restrict__ Wt,
    const unsigned short* __restrict__ mz, const float* __restrict__ bias,
    float* __restrict__ out, int nNodes) {
    __shared__ unsigned short sA[64][32];
    __shared__ unsigned short sB[64][32];

    int tid = threadIdx.x;
    int wave = tid >> 6;
    int lane = tid & 63;
    int lrow = lane & 15;
    int quad = lane >> 4;
    int node0 = blockIdx.x * 64;

    frag_cd acc[4];
#pragma unroll
    for (int ni = 0; ni < 4; ni++) acc[ni] = (frag_cd){0.f, 0.f, 0.f, 0.f};

    int ar = tid >> 2;
    int ak = (tid & 3) * 8;
    int aNode = node0 + ar;

    for (int kb = 0; kb < 256; kb += 32) {
        uint4 av = {0u, 0u, 0u, 0u};
        if (aNode < nNodes) av = *(const uint4*)(h + (size_t)aNode * DIN + kb + ak);
        *(uint4*)(&sA[ar][ak]) = av;
        *(uint4*)(&sB[ar][ak]) = *(const uint4*)(Wt + (size_t)ar * 256 + kb + ak);
        __syncthreads();

        frag_ab aF = *(const frag_ab*)(&sA[wave * 16 + lrow][quad * 8]);
#pragma unroll
        for (int ni = 0; ni < 4; ni++) {
            frag_ab bF = *(const frag_ab*)(&sB[ni * 16 + lrow][quad * 8]);
            acc[ni] = __builtin_amdgcn_mfma_f32_16x16x32_bf16(aF, bF, acc[ni], 0, 0, 0);
        }
        __syncthreads();
    }

#pragma unroll
    for (int r = 0; r < 4; r++) {
        int node = node0 + wave * 16 + quad * 4 + r;
        bool valid = (node < nNodes);
        float v[4];
#pragma unroll
        for (int ni = 0; ni < 4; ni++) {
            int colc = ni * 16 + lrow;
            if (colc < 40 && valid)
                v[ni] = acc[ni][r] + bias[colc] + bf2f(mz[(size_t)node * 64 + colc]);
            else
                v[ni] = -INFINITY;
        }
        float m = fmaxf(fmaxf(v[0], v[1]), fmaxf(v[2], v[3]));
#pragma unroll
        for (int off = 1; off < 16; off <<= 1) m = fmaxf(m, __shfl_xor(m, off));
        float s = 0.f;
#pragma unroll
        for (int ni = 0; ni < 4; ni++)
            if (v[ni] != -INFINITY) s += expf(v[ni] - m);
#pragma unroll
        for (int off = 1; off < 16; off <<= 1) s += __shfl_xor(s, off);
        float ls = logf(s);
#pragma unroll
        for (int ni = 0; ni < 4; ni++) {
            int colc = ni * 16 + lrow;
            if (valid && colc < 40)
                out[(size_t)node * 40 + colc] = v[ni] - m - ls;
        }
    }
}

extern "C" void kernel_launch(void* const* d_in, const int* in_sizes, int n_in,
                              void* d_out, int out_size, void* d_ws, size_t ws_size,
                              hipStream_t stream) {
    const float* x   = (const float*)d_in[0];
    const int*   ei  = (const int*)d_in[1];
    const float* Wl0 = (const float*)d_in[2];
    const float* Wr0 = (const float*)d_in[3];
    const float* b0  = (const float*)d_in[4];
    const float* Wl1 = (const float*)d_in[5];
    const float* Wr1 = (const float*)d_in[6];
    const float* b1  = (const float*)d_in[7];
    const float* Wl2 = (const float*)d_in[8];
    const float* Wr2 = (const float*)d_in[9];
    const float* b2  = (const float*)d_in[10];
    float* out = (float*)d_out;

    const int* src = ei;
    const int* dst = ei + N_EDGES;

    // ---- workspace layout ----
    const size_t NODE_PAD = 100352;
    char* ws = (char*)d_ws;
    int* cnt  = (int*)ws;  ws += NODE_PAD * sizeof(int);
    int* colv = (int*)ws;  ws += (size_t)NODE_PAD * SLOTS * sizeof(int);
    unsigned short* xbf  = (unsigned short*)ws; ws += (size_t)N_NODES * DIN * sizeof(unsigned short);
    unsigned short* mean = (unsigned short*)ws; ws += (size_t)N_NODES * DIN * sizeof(unsigned short);
    unsigned short* h1   = (unsigned short*)ws; ws += (size_t)N_NODES * DIN * sizeof(unsigned short);
    unsigned short* h2   = (unsigned short*)ws; ws += (size_t)N_NODES * DIN * sizeof(unsigned short);
    unsigned short* zb   = (unsigned short*)ws; ws += (size_t)N_NODES * 64 * sizeof(unsigned short);
    unsigned short* mz   = (unsigned short*)ws; ws += (size_t)N_NODES * 64 * sizeof(unsigned short);
    unsigned short* Wt0  = (unsigned short*)ws; ws += 256 * KTOT * sizeof(unsigned short);
    unsigned short* Wt1  = (unsigned short*)ws; ws += 256 * KTOT * sizeof(unsigned short);
    unsigned short* Wl2t = (unsigned short*)ws; ws += 64 * 256 * sizeof(unsigned short);
    unsigned short* Wr2t = (unsigned short*)ws; ws += 64 * 256 * sizeof(unsigned short);

    // ---- prep: bucket CSR + conversions, one launch ----
    hipMemsetAsync(cnt, 0, N_NODES * sizeof(int), stream);
    prep<<<32402, 256, 0, stream>>>(src, dst, cnt, colv, x, xbf,
                                    Wl0, Wr0, Wl1, Wr1, Wl2, Wr2,
                                    Wt0, Wt1, Wl2t, Wr2t);

    const int nodeBlocks = (N_NODES + 3) / 4;   // 25000
    const int mfmaBlocks = (N_NODES + 63) / 64;

    // ---- layer 0 ----
    gather_tile<256><<<dim3(nodeBlocks, 16), 256, 0, stream>>>(cnt, colv, xbf, mean, N_NODES);
    sage_mfma<<<mfmaBlocks, 256, 0, stream>>>(mean, xbf, Wt0, b0, h1, N_NODES);

    // ---- layer 1 ----
    gather_tile<256><<<dim3(nodeBlocks, 16), 256, 0, stream>>>(cnt, colv, h1, mean, N_NODES);
    sage_mfma<<<mfmaBlocks, 256, 0, stream>>>(mean, h1, Wt1, b1, h2, N_NODES);

    // ---- layer 2: transform-then-aggregate + fused logsoftmax ----
    mfma_lin64<<<mfmaBlocks, 256, 0, stream>>>(h2, Wl2t, zb, N_NODES);
    gather_tile<64><<<dim3(nodeBlocks, 4), 256, 0, stream>>>(cnt, colv, zb, mz, N_NODES);
    sage_out<<<mfmaBlocks, 256, 0, stream>>>(h2, Wr2t, mz, b2, out, N_NODES);
}

// Round 8
// 715.219 us; speedup vs baseline: 2.2199x; 2.2199x over previous
//
#include <hip/hip_runtime.h>
#include <hip/hip_bf16.h>
#include <math.h>

#define N_NODES 100000
#define N_EDGES 1600000
#define DIN 256
#define KTOT 512
#define SLOTS 64   // bucket capacity; deg ~ Poisson(16), P(>=64) ~ 1e-19

typedef __attribute__((ext_vector_type(8))) short frag_ab;   // 8 bf16
typedef __attribute__((ext_vector_type(4))) float frag_cd;   // 4 fp32

__device__ inline unsigned short f2bf(float f) {
    union { float f; unsigned u; } v; v.f = f;
    unsigned r = v.u + 0x7FFF + ((v.u >> 16) & 1);
    return (unsigned short)(r >> 16);
}
__device__ inline float bf2f(unsigned u16) {
    union { unsigned u; float f; } v; v.u = u16 << 16;
    return v.f;
}
__device__ inline float bf_lo(unsigned u) {
    union { unsigned u; float f; } v; v.u = u << 16; return v.f;
}
__device__ inline float bf_hi(unsigned u) {
    union { unsigned u; float f; } v; v.u = u & 0xffff0000u; return v.f;
}

// ======== prep mega-kernel: bucket-CSR + x->bf16 + weight transposes, one launch ========
// blocks [0,6250): bucket build; [6250,7402): weights; [7402,32402): conv x
__global__ __launch_bounds__(256) void prep(
    const int* __restrict__ src, const int* __restrict__ dst,
    int* __restrict__ cnt, int* __restrict__ col,
    const float* __restrict__ x, unsigned short* __restrict__ xbf,
    const float* __restrict__ Wl0, const float* __restrict__ Wr0,
    const float* __restrict__ Wl1, const float* __restrict__ Wr1,
    const float* __restrict__ Wl2, const float* __restrict__ Wr2,
    unsigned short* __restrict__ Wt0, unsigned short* __restrict__ Wt1,
    unsigned short* __restrict__ Wl2t, unsigned short* __restrict__ Wr2t) {
    int b = blockIdx.x;
    int tid = threadIdx.x;
    if (b < 6250) {
        int e = b * 256 + tid;   // < 1.6M exactly
        int d = dst[e];
        int pos = atomicAdd(&cnt[d], 1);
        if (pos < SLOTS) col[(size_t)d * SLOTS + pos] = src[e];
    } else if (b < 7402) {
        int idx = (b - 6250) * 256 + tid;
        if (idx < 262144) {
            const float* Wl = (idx < 131072) ? Wl0 : Wl1;
            const float* Wr = (idx < 131072) ? Wr0 : Wr1;
            unsigned short* Wt = (idx < 131072) ? Wt0 : Wt1;
            int i = idx & 131071;
            int n = i >> 9, k = i & 511;
            float v = (k < 256) ? Wl[k * 256 + n] : Wr[(k - 256) * 256 + n];
            Wt[i] = f2bf(v);
        } else if (idx < 294912) {
            const float* W = (idx < 278528) ? Wl2 : Wr2;
            unsigned short* Wt = (idx < 278528) ? Wl2t : Wr2t;
            int i = (idx - 262144) & 16383;
            int n = i >> 8, k = i & 255;
            Wt[i] = f2bf((n < 40) ? W[k * 40 + n] : 0.f);
        }
    } else {
        int i = (b - 7402) * 256 + tid;  // < 6.4M exactly
        float4 v = ((const float4*)x)[i];
        uint2 o;
        o.x = (unsigned)f2bf(v.x) | ((unsigned)f2bf(v.y) << 16);
        o.y = (unsigned)f2bf(v.z) | ((unsigned)f2bf(v.w) << 16);
        ((uint2*)xbf)[i] = o;
    }
}

#define ACC8(v) { a0 += bf_lo(v.x); a1 += bf_hi(v.x); a2 += bf_lo(v.y); a3 += bf_hi(v.y); \
                  a4 += bf_lo(v.z); a5 += bf_hi(v.z); a6 += bf_lo(v.w); a7 += bf_hi(v.w); }

// ------- gather-mean 256-wide: one wave per node, 2 edges parallel, 16-edge trips -------
__global__ __launch_bounds__(256) void gather_mean_bf(
    const int* __restrict__ cnt, const int* __restrict__ col,
    const unsigned short* __restrict__ h, unsigned short* __restrict__ mean, int nNodes) {
    int node = blockIdx.x * 4 + (threadIdx.x >> 6);
    int lane = threadIdx.x & 63;
    if (node >= nNodes) return;
    int deg = cnt[node];
    int nd = (deg < SLOTS) ? deg : SLOTS;
    const int* cp = col + (size_t)node * SLOTS;
    int half = lane >> 5;
    int l = lane & 31;
    float a0 = 0, a1 = 0, a2 = 0, a3 = 0, a4 = 0, a5 = 0, a6 = 0, a7 = 0;
    int e = 0;
    for (; e + 16 <= nd; e += 16) {
        int s0 = cp[e + half];
        int s1 = cp[e + 2 + half];
        int s2 = cp[e + 4 + half];
        int s3 = cp[e + 6 + half];
        int s4 = cp[e + 8 + half];
        int s5 = cp[e + 10 + half];
        int s6 = cp[e + 12 + half];
        int s7 = cp[e + 14 + half];
        uint4 v0 = *(const uint4*)(h + (size_t)s0 * DIN + l * 8);
        uint4 v1 = *(const uint4*)(h + (size_t)s1 * DIN + l * 8);
        uint4 v2 = *(const uint4*)(h + (size_t)s2 * DIN + l * 8);
        uint4 v3 = *(const uint4*)(h + (size_t)s3 * DIN + l * 8);
        uint4 v4 = *(const uint4*)(h + (size_t)s4 * DIN + l * 8);
        uint4 v5 = *(const uint4*)(h + (size_t)s5 * DIN + l * 8);
        uint4 v6 = *(const uint4*)(h + (size_t)s6 * DIN + l * 8);
        uint4 v7 = *(const uint4*)(h + (size_t)s7 * DIN + l * 8);
        ACC8(v0) ACC8(v1) ACC8(v2) ACC8(v3) ACC8(v4) ACC8(v5) ACC8(v6) ACC8(v7)
    }
    for (; e + 8 <= nd; e += 8) {
        int s0 = cp[e + half];
        int s1 = cp[e + 2 + half];
        int s2 = cp[e + 4 + half];
        int s3 = cp[e + 6 + half];
        uint4 v0 = *(const uint4*)(h + (size_t)s0 * DIN + l * 8);
        uint4 v1 = *(const uint4*)(h + (size_t)s1 * DIN + l * 8);
        uint4 v2 = *(const uint4*)(h + (size_t)s2 * DIN + l * 8);
        uint4 v3 = *(const uint4*)(h + (size_t)s3 * DIN + l * 8);
        ACC8(v0) ACC8(v1) ACC8(v2) ACC8(v3)
    }
    for (; e + 2 <= nd; e += 2) {
        int s = cp[e + half];
        uint4 v = *(const uint4*)(h + (size_t)s * DIN + l * 8);
        ACC8(v)
    }
    if (e < nd && half == 0) {
        int s = cp[e];
        uint4 v = *(const uint4*)(h + (size_t)s * DIN + l * 8);
        ACC8(v)
    }
    a0 += __shfl_xor(a0, 32); a1 += __shfl_xor(a1, 32);
    a2 += __shfl_xor(a2, 32); a3 += __shfl_xor(a3, 32);
    a4 += __shfl_xor(a4, 32); a5 += __shfl_xor(a5, 32);
    a6 += __shfl_xor(a6, 32); a7 += __shfl_xor(a7, 32);
    if (half == 0) {
        float inv = 1.0f / fmaxf((float)deg, 1.0f);
        uint4 o;
        o.x = (unsigned)f2bf(a0 * inv) | ((unsigned)f2bf(a1 * inv) << 16);
        o.y = (unsigned)f2bf(a2 * inv) | ((unsigned)f2bf(a3 * inv) << 16);
        o.z = (unsigned)f2bf(a4 * inv) | ((unsigned)f2bf(a5 * inv) << 16);
        o.w = (unsigned)f2bf(a6 * inv) | ((unsigned)f2bf(a7 * inv) << 16);
        *(uint4*)(mean + (size_t)node * DIN + l * 8) = o;
    }
}

// ------- gather-mean 64-wide (z rows): one wave per node, 4 edges parallel ----
__global__ __launch_bounds__(256) void gather_mean64(
    const int* __restrict__ cnt, const int* __restrict__ col,
    const unsigned short* __restrict__ z, unsigned short* __restrict__ mz, int nNodes) {
    int node = blockIdx.x * 4 + (threadIdx.x >> 6);
    int lane = threadIdx.x & 63;
    if (node >= nNodes) return;
    int deg = cnt[node];
    int nd = (deg < SLOTS) ? deg : SLOTS;
    const int* cp = col + (size_t)node * SLOTS;
    int g = lane >> 4;
    int l = lane & 15;
    float a0 = 0, a1 = 0, a2 = 0, a3 = 0;
    int e = 0;
    for (; e + 8 <= nd; e += 8) {
        int s0 = cp[e + g];
        int s1 = cp[e + 4 + g];
        uint2 v0 = *(const uint2*)(z + (size_t)s0 * 64 + l * 4);
        uint2 v1 = *(const uint2*)(z + (size_t)s1 * 64 + l * 4);
        a0 += bf_lo(v0.x); a1 += bf_hi(v0.x); a2 += bf_lo(v0.y); a3 += bf_hi(v0.y);
        a0 += bf_lo(v1.x); a1 += bf_hi(v1.x); a2 += bf_lo(v1.y); a3 += bf_hi(v1.y);
    }
    for (; e + 4 <= nd; e += 4) {
        int s = cp[e + g];
        uint2 v = *(const uint2*)(z + (size_t)s * 64 + l * 4);
        a0 += bf_lo(v.x); a1 += bf_hi(v.x); a2 += bf_lo(v.y); a3 += bf_hi(v.y);
    }
    int rem = nd - e;
    if (g < rem) {
        int s = cp[e + g];
        uint2 v = *(const uint2*)(z + (size_t)s * 64 + l * 4);
        a0 += bf_lo(v.x); a1 += bf_hi(v.x); a2 += bf_lo(v.y); a3 += bf_hi(v.y);
    }
    a0 += __shfl_xor(a0, 16); a1 += __shfl_xor(a1, 16);
    a2 += __shfl_xor(a2, 16); a3 += __shfl_xor(a3, 16);
    a0 += __shfl_xor(a0, 32); a1 += __shfl_xor(a1, 32);
    a2 += __shfl_xor(a2, 32); a3 += __shfl_xor(a3, 32);
    if (lane < 16) {
        float inv = 1.0f / fmaxf((float)deg, 1.0f);
        uint2 o;
        o.x = (unsigned)f2bf(a0 * inv) | ((unsigned)f2bf(a1 * inv) << 16);
        o.y = (unsigned)f2bf(a2 * inv) | ((unsigned)f2bf(a3 * inv) << 16);
        *(uint2*)(mz + (size_t)node * 64 + l * 4) = o;
    }
}

// ---- MFMA dual-GEMM (layers 0/1): out = relu([mean;h] @ Wt^T + b), bf16 out ----
// 512 threads (8 waves), M-tile = 128 nodes, N = 256 cols, BK = 32.
// Wave w: row-group (w&1) covers mtiles (w&1)*4.. ; col-group (w>>1) covers ntiles (w>>1)*4..
__global__ __launch_bounds__(512) void sage_mfma(
    const unsigned short* __restrict__ mean, const unsigned short* __restrict__ h,
    const unsigned short* __restrict__ Wt, const float* __restrict__ bias,
    unsigned short* __restrict__ out, int nNodes) {
    __shared__ unsigned short sA[128][32];   // 8 KB
    __shared__ unsigned short sB[256][32];   // 16 KB

    int tid = threadIdx.x;
    int wave = tid >> 6;          // 0..7
    int lane = tid & 63;
    int lrow = lane & 15;
    int quad = lane >> 4;
    int node0 = blockIdx.x * 128;
    int mg = wave & 1;            // row group
    int ng = wave >> 1;           // col group

    frag_cd acc[4][4];
#pragma unroll
    for (int mi = 0; mi < 4; mi++)
#pragma unroll
        for (int ni = 0; ni < 4; ni++) acc[mi][ni] = (frag_cd){0.f, 0.f, 0.f, 0.f};

    int ar = tid >> 2;            // 0..127
    int ak = (tid & 3) * 8;
    int aNode = node0 + ar;
    int br = tid >> 1;            // 0..255
    int bk = (tid & 1) * 16;

    for (int kb = 0; kb < KTOT; kb += 32) {
        {
            const unsigned short* srcp = (kb < 256)
                ? (mean + (size_t)aNode * DIN + kb + ak)
                : (h + (size_t)aNode * DIN + (kb - 256) + ak);
            uint4 av = {0u, 0u, 0u, 0u};
            if (aNode < nNodes) av = *(const uint4*)srcp;
            *(uint4*)(&sA[ar][ak]) = av;
        }
        {
            const unsigned short* wp = Wt + (size_t)br * KTOT + kb + bk;
            *(uint4*)(&sB[br][bk]) = *(const uint4*)(wp);
            *(uint4*)(&sB[br][bk + 8]) = *(const uint4*)(wp + 8);
        }
        __syncthreads();

        frag_ab aF[4], bF[4];
#pragma unroll
        for (int mi = 0; mi < 4; mi++)
            aF[mi] = *(const frag_ab*)(&sA[(mg * 4 + mi) * 16 + lrow][quad * 8]);
#pragma unroll
        for (int ni = 0; ni < 4; ni++)
            bF[ni] = *(const frag_ab*)(&sB[(ng * 4 + ni) * 16 + lrow][quad * 8]);

#pragma unroll
        for (int mi = 0; mi < 4; mi++)
#pragma unroll
            for (int ni = 0; ni < 4; ni++)
                acc[mi][ni] = __builtin_amdgcn_mfma_f32_16x16x32_bf16(
                    aF[mi], bF[ni], acc[mi][ni], 0, 0, 0);
        __syncthreads();
    }

#pragma unroll
    for (int ni = 0; ni < 4; ni++) {
        int colc = (ng * 4 + ni) * 16 + lrow;
        float bv = bias[colc];
#pragma unroll
        for (int mi = 0; mi < 4; mi++) {
#pragma unroll
            for (int r = 0; r < 4; r++) {
                int node = node0 + (mg * 4 + mi) * 16 + quad * 4 + r;
                if (node < nNodes) {
                    float v = fmaxf(acc[mi][ni][r] + bv, 0.f);
                    out[(size_t)node * 256 + colc] = f2bf(v);
                }
            }
        }
    }
}

// ---------------- z = h @ Wt64^T (K=256, 64 cols, bf16 out, no bias) ----------------
__global__ __launch_bounds__(256) void mfma_lin64(
    const unsigned short* __restrict__ h, const unsigned short* __restrict__ Wt,
    unsigned short* __restrict__ z, int nNodes) {
    __shared__ unsigned short sA[64][32];
    __shared__ unsigned short sB[64][32];

    int tid = threadIdx.x;
    int wave = tid >> 6;
    int lane = tid & 63;
    int lrow = lane & 15;
    int quad = lane >> 4;
    int node0 = blockIdx.x * 64;

    frag_cd acc[4];
#pragma unroll
    for (int ni = 0; ni < 4; ni++) acc[ni] = (frag_cd){0.f, 0.f, 0.f, 0.f};

    int ar = tid >> 2;
    int ak = (tid & 3) * 8;
    int aNode = node0 + ar;

    for (int kb = 0; kb < 256; kb += 32) {
        uint4 av = {0u, 0u, 0u, 0u};
        if (aNode < nNodes) av = *(const uint4*)(h + (size_t)aNode * DIN + kb + ak);
        *(uint4*)(&sA[ar][ak]) = av;
        *(uint4*)(&sB[ar][ak]) = *(const uint4*)(Wt + (size_t)ar * 256 + kb + ak);
        __syncthreads();

        frag_ab aF = *(const frag_ab*)(&sA[wave * 16 + lrow][quad * 8]);
#pragma unroll
        for (int ni = 0; ni < 4; ni++) {
            frag_ab bF = *(const frag_ab*)(&sB[ni * 16 + lrow][quad * 8]);
            acc[ni] = __builtin_amdgcn_mfma_f32_16x16x32_bf16(aF, bF, acc[ni], 0, 0, 0);
        }
        __syncthreads();
    }

#pragma unroll
    for (int ni = 0; ni < 4; ni++) {
        int colc = ni * 16 + lrow;
#pragma unroll
        for (int r = 0; r < 4; r++) {
            int node = node0 + wave * 16 + quad * 4 + r;
            if (node < nNodes)
                z[(size_t)node * 64 + colc] = f2bf(acc[ni][r]);
        }
    }
}

// ------- final: out = log_softmax(h2 @ Wr2t^T + mean_z + b2), fp32 out (40 cols) -------
__global__ __launch_bounds__(256) void sage_out(
    const unsigned short* __restrict__ h, const unsigned short* __restrict__ Wt,
    const unsigned short* __restrict__ mz, const float* __restrict__ bias,
    float* __restrict__ out, int nNodes) {
    __shared__ unsigned short sA[64][32];
    __shared__ unsigned short sB[64][32];

    int tid = threadIdx.x;
    int wave = tid >> 6;
    int lane = tid & 63;
    int lrow = lane & 15;
    int quad = lane >> 4;
    int node0 = blockIdx.x * 64;

    frag_cd acc[4];
#pragma unroll
    for (int ni = 0; ni < 4; ni++) acc[ni] = (frag_cd){0.f, 0.f, 0.f, 0.f};

    int ar = tid >> 2;
    int ak = (tid & 3) * 8;
    int aNode = node0 + ar;

    for (int kb = 0; kb < 256; kb += 32) {
        uint4 av = {0u, 0u, 0u, 0u};
        if (aNode < nNodes) av = *(const uint4*)(h + (size_t)aNode * DIN + kb + ak);
        *(uint4*)(&sA[ar][ak]) = av;
        *(uint4*)(&sB[ar][ak]) = *(const uint4*)(Wt + (size_t)ar * 256 + kb + ak);
        __syncthreads();

        frag_ab aF = *(const frag_ab*)(&sA[wave * 16 + lrow][quad * 8]);
#pragma unroll
        for (int ni = 0; ni < 4; ni++) {
            frag_ab bF = *(const frag_ab*)(&sB[ni * 16 + lrow][quad * 8]);
            acc[ni] = __builtin_amdgcn_mfma_f32_16x16x32_bf16(aF, bF, acc[ni], 0, 0, 0);
        }
        __syncthreads();
    }

#pragma unroll
    for (int r = 0; r < 4; r++) {
        int node = node0 + wave * 16 + quad * 4 + r;
        bool valid = (node < nNodes);
        float v[4];
#pragma unroll
        for (int ni = 0; ni < 4; ni++) {
            int colc = ni * 16 + lrow;
            if (colc < 40 && valid)
                v[ni] = acc[ni][r] + bias[colc] + bf2f(mz[(size_t)node * 64 + colc]);
            else
                v[ni] = -INFINITY;
        }
        float m = fmaxf(fmaxf(v[0], v[1]), fmaxf(v[2], v[3]));
#pragma unroll
        for (int off = 1; off < 16; off <<= 1) m = fmaxf(m, __shfl_xor(m, off));
        float s = 0.f;
#pragma unroll
        for (int ni = 0; ni < 4; ni++)
            if (v[ni] != -INFINITY) s += expf(v[ni] - m);
#pragma unroll
        for (int off = 1; off < 16; off <<= 1) s += __shfl_xor(s, off);
        float ls = logf(s);
#pragma unroll
        for (int ni = 0; ni < 4; ni++) {
            int colc = ni * 16 + lrow;
            if (valid && colc < 40)
                out[(size_t)node * 40 + colc] = v[ni] - m - ls;
        }
    }
}

extern "C" void kernel_launch(void* const* d_in, const int* in_sizes, int n_in,
                              void* d_out, int out_size, void* d_ws, size_t ws_size,
                              hipStream_t stream) {
    const float* x   = (const float*)d_in[0];
    const int*   ei  = (const int*)d_in[1];
    const float* Wl0 = (const float*)d_in[2];
    const float* Wr0 = (const float*)d_in[3];
    const float* b0  = (const float*)d_in[4];
    const float* Wl1 = (const float*)d_in[5];
    const float* Wr1 = (const float*)d_in[6];
    const float* b1  = (const float*)d_in[7];
    const float* Wl2 = (const float*)d_in[8];
    const float* Wr2 = (const float*)d_in[9];
    const float* b2  = (const float*)d_in[10];
    float* out = (float*)d_out;

    const int* src = ei;
    const int* dst = ei + N_EDGES;

    // ---- workspace layout ----
    const size_t NODE_PAD = 100352;
    char* ws = (char*)d_ws;
    int* cnt  = (int*)ws;  ws += NODE_PAD * sizeof(int);
    int* colv = (int*)ws;  ws += (size_t)NODE_PAD * SLOTS * sizeof(int);
    unsigned short* xbf  = (unsigned short*)ws; ws += (size_t)N_NODES * DIN * sizeof(unsigned short);
    unsigned short* mean = (unsigned short*)ws; ws += (size_t)N_NODES * DIN * sizeof(unsigned short);
    unsigned short* h1   = (unsigned short*)ws; ws += (size_t)N_NODES * DIN * sizeof(unsigned short);
    unsigned short* h2   = (unsigned short*)ws; ws += (size_t)N_NODES * DIN * sizeof(unsigned short);
    unsigned short* zb   = (unsigned short*)ws; ws += (size_t)N_NODES * 64 * sizeof(unsigned short);
    unsigned short* mz   = (unsigned short*)ws; ws += (size_t)N_NODES * 64 * sizeof(unsigned short);
    unsigned short* Wt0  = (unsigned short*)ws; ws += 256 * KTOT * sizeof(unsigned short);
    unsigned short* Wt1  = (unsigned short*)ws; ws += 256 * KTOT * sizeof(unsigned short);
    unsigned short* Wl2t = (unsigned short*)ws; ws += 64 * 256 * sizeof(unsigned short);
    unsigned short* Wr2t = (unsigned short*)ws; ws += 64 * 256 * sizeof(unsigned short);

    // ---- prep: bucket CSR + conversions, one launch ----
    hipMemsetAsync(cnt, 0, N_NODES * sizeof(int), stream);
    prep<<<32402, 256, 0, stream>>>(src, dst, cnt, colv, x, xbf,
                                    Wl0, Wr0, Wl1, Wr1, Wl2, Wr2,
                                    Wt0, Wt1, Wl2t, Wr2t);

    const int nodeBlocks = (N_NODES + 3) / 4;      // 25000
    const int mfmaBlocks128 = (N_NODES + 127) / 128;  // 782
    const int mfmaBlocks64 = (N_NODES + 63) / 64;     // 1563

    // ---- layer 0 ----
    gather_mean_bf<<<nodeBlocks, 256, 0, stream>>>(cnt, colv, xbf, mean, N_NODES);
    sage_mfma<<<mfmaBlocks128, 512, 0, stream>>>(mean, xbf, Wt0, b0, h1, N_NODES);

    // ---- layer 1 ----
    gather_mean_bf<<<nodeBlocks, 256, 0, stream>>>(cnt, colv, h1, mean, N_NODES);
    sage_mfma<<<mfmaBlocks128, 512, 0, stream>>>(mean, h1, Wt1, b1, h2, N_NODES);

    // ---- layer 2: transform-then-aggregate + fused logsoftmax ----
    mfma_lin64<<<mfmaBlocks64, 256, 0, stream>>>(h2, Wl2t, zb, N_NODES);
    gather_mean64<<<nodeBlocks, 256, 0, stream>>>(cnt, colv, zb, mz, N_NODES);
    sage_out<<<mfmaBlocks64, 256, 0, stream>>>(h2, Wr2t, mz, b2, out, N_NODES);
}